// Round 12
// baseline (219.305 us; speedup 1.0000x reference)
//
#include <hip/hip_runtime.h>
#include <hip/hip_bf16.h>
#include <math.h>

#define N_FEAT 32
#define N_HID  64   // 2*N_FEAT
#define N_LAT  64
#define R_HID  128  // 2*N_LAT
#define TILES_PER_WAVE 8    // 128 tracks/wave -> 15625 waves
#define STREAM (4 * TILES_PER_WAVE)   // 32 contiguous tracks per lane-group
#define H1W 88              // h1 bf16 row stride in shorts (176B, aligned b128 rows)

typedef short s16x8 __attribute__((ext_vector_type(8)));
typedef float f32x4 __attribute__((ext_vector_type(4)));
typedef int   i32x4 __attribute__((ext_vector_type(4)));

__device__ __forceinline__ short bfs(float f) {          // f32 -> bf16 bits (RNE)
    __bf16 b = (__bf16)f;
    return __builtin_bit_cast(short, b);
}
__device__ __forceinline__ float bff(short s) {          // bf16 bits -> f32 (exact)
    return (float)__builtin_bit_cast(__bf16, s);
}
__device__ __forceinline__ f32x4 mfma16(s16x8 a, s16x8 b, f32x4 c) {
    return __builtin_amdgcn_mfma_f32_16x16x32_bf16(a, b, c, 0, 0, 0);
}
__device__ __forceinline__ float rdlane(float v, int l) {
    return __int_as_float(__builtin_amdgcn_readlane(__float_as_int(v), l));
}
__device__ __forceinline__ void split8(f32x4 a, f32x4 b, s16x8& h, s16x8& l) {
    #pragma unroll
    for (int j = 0; j < 4; ++j) {
        short h0 = bfs(a[j]); h[j] = h0;     l[j] = bfs(a[j] - bff(h0));
        short h1 = bfs(b[j]); h[4 + j] = h1; l[4 + j] = bfs(b[j] - bff(h1));
    }
}

// B-frag loader: lane (g,r), tile col c: b[j] = w[(k0+j)*64 + c], split hi/lo.
__device__ __forceinline__ void load_bfrag(const float* __restrict__ w, int k0, int c,
                                           s16x8& hi, s16x8& lo) {
    #pragma unroll
    for (int j = 0; j < 8; ++j) {
        float f = w[(size_t)(k0 + j) * 64 + c];
        short h = bfs(f);
        hi[j] = h;
        lo[j] = bfs(f - bff(h));
    }
}

// ---------------------------------------------------------------------------
// Fast zero of the pooled accumulator. Round-12 finding: hipMemsetAsync's
// rocclr fillBufferAligned ran at 171 GB/s (150 us for 25.6 MB = 70% of the
// whole budget). Grid-stride float4 stores run at HBM write BW (~10 us).
// ---------------------------------------------------------------------------
__global__ __launch_bounds__(256) void zero_kernel(f32x4* __restrict__ p, int n4)
{
    int i = blockIdx.x * blockDim.x + threadIdx.x;
    int stride = gridDim.x * blockDim.x;
    f32x4 z = {0.f, 0.f, 0.f, 0.f};
    for (; i < n4; i += stride) p[i] = z;
}

// ---------------------------------------------------------------------------
// phi via bf16 MFMA (L1: x-hi/lo x W1-hi/lo = 12 MFMA; h1 staged bf16;
// L2: h1 x W2-hi/lo = 16 MFMA). Contiguous-stream pooling (round-11,
// validated: dur tracks atomic flush traffic; contiguous streams flush only
// at true event boundaries).
// MFMA layouts (m89/m91-verified): A: row=l&15, k=8*(l>>4)+j; B: col=l&15,
// k=8*(l>>4)+j; C/D: col=l&15, row=4*(l>>4)+reg.  C-row 4g+q of tile t is
// track wbase + g*32 + 4t + q == group g's stream, in order.
// ---------------------------------------------------------------------------
__global__ __launch_bounds__(256, 4) void phi_mfma_kernel(
    const float* __restrict__ x,
    const int*   __restrict__ eids,
    const float* __restrict__ w1, const float* __restrict__ b1,
    const float* __restrict__ w2, const float* __restrict__ b2,
    float* __restrict__ pooled, int n_tracks)
{
    // W2 frags: [4s+n] = hi, [8+4s+n] = lo
    __shared__ s16x8 wfrag[16][64];          // 16 KB
    __shared__ short h1s[4][16 * H1W];       // bf16 h1, 2816 B per wave

    const int lane = threadIdx.x & 63;
    const int wv   = threadIdx.x >> 6;
    const int g    = lane >> 4;   // 0..3
    const int r    = lane & 15;   // 0..15
    const int sg   = r >> 2;      // stream of A-row r
    const int so   = r & 3;       // offset within the stream's 4-track window

    // ---- one-time cooperative pack of W2 frags ----
    #pragma unroll
    for (int ff = 0; ff < 4; ++ff) {
        int f   = wv + 4 * ff;
        int idx = f & 7;
        int s   = idx >> 2;
        int n   = idx & 3;
        bool lo = (f >= 8);
        s16x8 v;
        #pragma unroll
        for (int j = 0; j < 8; ++j) {
            float fv = w2[(size_t)(32 * s + 8 * g + j) * 64 + (r + 16 * n)];
            short h  = bfs(fv);
            v[j] = lo ? bfs(fv - bff(h)) : h;
        }
        wfrag[f][lane] = v;
    }
    __syncthreads();

    short* h1w = h1s[wv];
    const long long wbase = ((long long)blockIdx.x * 4 + wv) * (4LL * STREAM);
    if (wbase >= n_tracks) return;   // after the only barrier -> safe

    // ---- W1 hi/lo frags in VGPRs (32 regs) ----
    s16x8 w1h[4], w1l[4];
    #pragma unroll
    for (int n = 0; n < 4; ++n) load_bfrag(w1, 8 * g, r + 16 * n, w1h[n], w1l[n]);

    float b1v[4], b2v[4];
    #pragma unroll
    for (int n = 0; n < 4; ++n) { b1v[n] = b1[r + 16 * n]; b2v[n] = b2[r + 16 * n]; }

    // x loader: A-row r of tile T <- track wbase + sg*STREAM + 4T + so
    #define LOADX(T, XA, XB) {                                                    \
        long long row_ = wbase + (long long)sg * STREAM + 4 * (T) + so;           \
        if (row_ > n_tracks - 1) row_ = n_tracks - 1;                             \
        XA = *(const f32x4*)(x + row_ * N_FEAT + 8 * g);                          \
        XB = *(const f32x4*)(x + row_ * N_FEAT + 8 * g + 4);                      \
    }

    // ---- prologue: tile 0 x ----
    f32x4 xa, xb;
    LOADX(0, xa, xb)

    float carry[4] = {0.f, 0.f, 0.f, 0.f};
    int carry_id = -1;
    int dyn = 0;   // opaque 0: keeps wfrag reads per-tile (defeats LICM reg-hoist)

    #pragma unroll 1
    for (int t = 0; t < TILES_PER_WAVE; ++t) {
        asm volatile("" : "+v"(dyn));
        const s16x8* wfl = (const s16x8*)&wfrag[0][lane] + dyn;

        // event ids for group g's current 4-track window (contiguous stream)
        long long tbg = wbase + (long long)g * STREAM + 4 * t;   // group window base
        long long ib = tbg;
        if (ib > n_tracks - 4) ib = (n_tracks - 4) & ~3LL;
        i32x4 e4 = *(const i32x4*)(eids + ib);

        // ---- split current x to hi/lo A-frags; prefetch next tile ----
        s16x8 xh, xl;
        split8(xa, xb, xh, xl);
        if (t + 1 < TILES_PER_WAVE) LOADX(t + 1, xa, xb)

        // ---- layer 1: 12 MFMA (W1 from regs) ----
        f32x4 h1C[4];
        #pragma unroll
        for (int n = 0; n < 4; ++n) {
            f32x4 c = {0.f, 0.f, 0.f, 0.f};
            c = mfma16(xl, w1h[n], c);
            c = mfma16(xh, w1l[n], c);
            c = mfma16(xh, w1h[n], c);
            h1C[n] = c;
        }

        // ---- bias+relu, stage h1 as bf16 ----
        #pragma unroll
        for (int n = 0; n < 4; ++n)
            #pragma unroll
            for (int q = 0; q < 4; ++q)
                h1w[(4 * g + q) * H1W + r + 16 * n] =
                    bfs(fmaxf(h1C[n][q] + b1v[n], 0.f));

        // ---- read back h1 rows: 2 b128 = ready A-frags (no extraction) ----
        s16x8 ah0 = *(const s16x8*)&h1w[r * H1W + 8 * g];        // k = 0..31
        s16x8 ah1 = *(const s16x8*)&h1w[r * H1W + 32 + 8 * g];   // k = 32..63

        // ---- layer 2: 16 MFMA (W2 hi/lo frags from LDS) ----
        f32x4 h2C[4] = {{0.f,0.f,0.f,0.f},{0.f,0.f,0.f,0.f},{0.f,0.f,0.f,0.f},{0.f,0.f,0.f,0.f}};
        #pragma unroll
        for (int n = 0; n < 4; ++n) {
            h2C[n] = mfma16(ah0, wfl[64 * (8 + n)], h2C[n]);       // lo s0
            h2C[n] = mfma16(ah0, wfl[64 * n],       h2C[n]);       // hi s0
            h2C[n] = mfma16(ah1, wfl[64 * (12 + n)], h2C[n]);      // lo s1
            h2C[n] = mfma16(ah1, wfl[64 * (4 + n)],  h2C[n]);      // hi s1
        }

        // ---- bias+relu+pool: contiguous-stream run carry ----
        int remg = (int)(n_tracks - tbg);            // valid tracks in window
        remg = remg < 0 ? 0 : (remg > 4 ? 4 : remg);
        const bool newrun   = (e4[0] != carry_id);   // adjacent-track boundary
        const bool doflush0 = newrun && (carry_id >= 0);
        const bool q01 = (e4[1] != e4[0]);
        const bool q12 = (e4[2] != e4[1]);
        const bool q23 = (e4[3] != e4[2]);
        #pragma unroll
        for (int n = 0; n < 4; ++n) {
            f32x4 hv;
            #pragma unroll
            for (int q = 0; q < 4; ++q) {
                float fq = fmaxf(h2C[n][q] + b2v[n], 0.f);
                hv[q] = (q < remg) ? fq : 0.f;
            }
            float* pp = pooled + (size_t)(r + 16 * n);
            float c = carry[n];
            if (doflush0) atomicAdd(pp + (size_t)carry_id * N_LAT, c);
            if (newrun)   c = 0.f;
            c += hv[0];
            if (q01) { atomicAdd(pp + (size_t)e4[0] * N_LAT, c); c = 0.f; }
            c += hv[1];
            if (q12) { atomicAdd(pp + (size_t)e4[1] * N_LAT, c); c = 0.f; }
            c += hv[2];
            if (q23) { atomicAdd(pp + (size_t)e4[2] * N_LAT, c); c = 0.f; }
            c += hv[3];
            carry[n] = c;
        }
        carry_id = e4[3];
    }

    if (carry_id >= 0) {
        #pragma unroll
        for (int n = 0; n < 4; ++n)
            atomicAdd(pooled + (size_t)carry_id * N_LAT + r + 16 * n, carry[n]);
    }
    #undef LOADX
}

// ---------------------------------------------------------------------------
// rho, wave-parallel (unchanged; next target if it tops the profile).
// ---------------------------------------------------------------------------
__global__ __launch_bounds__(512) void rho_kernel(
    const float* __restrict__ pooled,
    const float* __restrict__ w1, const float* __restrict__ b1,
    const float* __restrict__ w2, const float* __restrict__ b2,
    const float* __restrict__ w3, const float* __restrict__ b3,
    float* __restrict__ out, int n_events)
{
    __shared__ float lw1[N_LAT * R_HID];
    __shared__ float lw2[R_HID * N_LAT];
    __shared__ float lbias[R_HID + N_LAT + N_LAT + 1];
    {
        int tid = threadIdx.x;
        for (int i = tid; i < N_LAT * R_HID; i += 512) lw1[i] = w1[i];
        for (int i = tid; i < R_HID * N_LAT; i += 512) lw2[i] = w2[i];
        if (tid < R_HID) lbias[tid] = b1[tid];
        if (tid < N_LAT) lbias[R_HID + tid] = b2[tid];
        if (tid < N_LAT) lbias[R_HID + N_LAT + tid] = w3[tid];
        if (tid == 0)    lbias[R_HID + 2 * N_LAT] = b3[0];
    }
    __syncthreads();

    const int lane = threadIdx.x & 63;
    const long long ebase = ((long long)blockIdx.x * 8 + (threadIdx.x >> 6)) * 8;
    if (ebase >= n_events) return;

    const float b1va = lbias[lane];
    const float b1vb = lbias[64 + lane];
    const float b2v  = lbias[R_HID + lane];
    const float w3v  = lbias[R_HID + N_LAT + lane];
    const float b3v  = lbias[R_HID + 2 * N_LAT];

    float pe[8];
    #pragma unroll
    for (int i = 0; i < 8; ++i) {
        long long e = ebase + i;
        pe[i] = (e < n_events) ? pooled[e * N_LAT + lane] : 0.f;
    }

    float r1a[8], r1b[8];
    #pragma unroll
    for (int i = 0; i < 8; ++i) { r1a[i] = b1va; r1b[i] = b1vb; }
    #pragma unroll 2
    for (int k = 0; k < N_LAT; ++k) {
        float wA = lw1[k * R_HID + lane];
        float wB = lw1[k * R_HID + 64 + lane];
        #pragma unroll
        for (int i = 0; i < 8; ++i) {
            float s = rdlane(pe[i], k);
            r1a[i] = fmaf(s, wA, r1a[i]);
            r1b[i] = fmaf(s, wB, r1b[i]);
        }
    }
    #pragma unroll
    for (int i = 0; i < 8; ++i) {
        r1a[i] = fmaxf(r1a[i], 0.f);
        r1b[i] = fmaxf(r1b[i], 0.f);
    }

    float r2[8];
    #pragma unroll
    for (int i = 0; i < 8; ++i) r2[i] = b2v;
    #pragma unroll 2
    for (int k = 0; k < 64; ++k) {
        float w = lw2[k * N_LAT + lane];
        #pragma unroll
        for (int i = 0; i < 8; ++i) r2[i] = fmaf(rdlane(r1a[i], k), w, r2[i]);
    }
    #pragma unroll 2
    for (int k = 0; k < 64; ++k) {
        float w = lw2[(64 + k) * N_LAT + lane];
        #pragma unroll
        for (int i = 0; i < 8; ++i) r2[i] = fmaf(rdlane(r1b[i], k), w, r2[i]);
    }

    float zv = 0.f;
    #pragma unroll
    for (int i = 0; i < 8; ++i) {
        float tv = fmaxf(r2[i], 0.f) * w3v;
        #pragma unroll
        for (int off = 32; off >= 1; off >>= 1) tv += __shfl_xor(tv, off, 64);
        zv = (lane == i) ? tv : zv;
    }
    if (lane < 8 && ebase + lane < n_events)
        out[ebase + lane] = 1.f / (1.f + expf(-(zv + b3v)));
}

extern "C" void kernel_launch(void* const* d_in, const int* in_sizes, int n_in,
                              void* d_out, int out_size, void* d_ws, size_t ws_size,
                              hipStream_t stream) {
    const float* x      = (const float*)d_in[0];
    const int*   eids   = (const int*)  d_in[1];
    const float* phi_w1 = (const float*)d_in[2];
    const float* phi_b1 = (const float*)d_in[3];
    const float* phi_w2 = (const float*)d_in[4];
    const float* phi_b2 = (const float*)d_in[5];
    const float* rho_w1 = (const float*)d_in[6];
    const float* rho_b1 = (const float*)d_in[7];
    const float* rho_w2 = (const float*)d_in[8];
    const float* rho_b2 = (const float*)d_in[9];
    const float* rho_w3 = (const float*)d_in[10];
    const float* rho_b3 = (const float*)d_in[11];
    float* out = (float*)d_out;

    int n_tracks = in_sizes[1];
    int n_events = out_size;

    float* pooled = (float*)d_ws;  // [n_events, 64] accumulator

    // custom zero (rocclr fill ran at 171 GB/s = 150 us; this is ~10 us)
    int n4 = n_events * N_LAT / 4;
    zero_kernel<<<2048, 256, 0, stream>>>((f32x4*)pooled, n4);

    long long tracks_per_wave = 4LL * STREAM;   // 128
    long long waves  = ((long long)n_tracks + tracks_per_wave - 1) / tracks_per_wave;
    int phi_blocks   = (int)((waves + 3) / 4);
    phi_mfma_kernel<<<phi_blocks, 256, 0, stream>>>(
        x, eids, phi_w1, phi_b1, phi_w2, phi_b2, pooled, n_tracks);

    long long ewaves = ((long long)n_events + 7) / 8;
    int rho_blocks = (int)((ewaves + 7) / 8);
    rho_kernel<<<rho_blocks, 512, 0, stream>>>(
        pooled, rho_w1, rho_b1, rho_w2, rho_b2, rho_w3, rho_b3, out, n_events);
}

// Round 13
// 125.044 us; speedup vs baseline: 1.7538x; 1.7538x over previous
//
#include <hip/hip_runtime.h>
#include <hip/hip_bf16.h>
#include <math.h>

#define N_FEAT 32
#define N_HID  64   // 2*N_FEAT
#define N_LAT  64
#define R_HID  128  // 2*N_LAT
#define TILES_PER_WAVE 8    // 128 tracks/wave -> 15625 waves
#define STREAM (4 * TILES_PER_WAVE)   // 32 contiguous tracks per lane-group
#define H1W 88              // h1 bf16 row stride in shorts (176B, aligned b128 rows)
#define R1W 136             // r1 bf16 row stride in shorts (272B, b128-aligned rows)

typedef short s16x8 __attribute__((ext_vector_type(8)));
typedef float f32x4 __attribute__((ext_vector_type(4)));
typedef int   i32x4 __attribute__((ext_vector_type(4)));

__device__ __forceinline__ short bfs(float f) {          // f32 -> bf16 bits (RNE)
    __bf16 b = (__bf16)f;
    return __builtin_bit_cast(short, b);
}
__device__ __forceinline__ float bff(short s) {          // bf16 bits -> f32 (exact)
    return (float)__builtin_bit_cast(__bf16, s);
}
__device__ __forceinline__ f32x4 mfma16(s16x8 a, s16x8 b, f32x4 c) {
    return __builtin_amdgcn_mfma_f32_16x16x32_bf16(a, b, c, 0, 0, 0);
}
__device__ __forceinline__ void split8(f32x4 a, f32x4 b, s16x8& h, s16x8& l) {
    #pragma unroll
    for (int j = 0; j < 4; ++j) {
        short h0 = bfs(a[j]); h[j] = h0;     l[j] = bfs(a[j] - bff(h0));
        short h1 = bfs(b[j]); h[4 + j] = h1; l[4 + j] = bfs(b[j] - bff(h1));
    }
}

// B-frag loader: lane (g,r), tile col c: b[j] = w[(k0+j)*64 + c], split hi/lo.
__device__ __forceinline__ void load_bfrag(const float* __restrict__ w, int k0, int c,
                                           s16x8& hi, s16x8& lo) {
    #pragma unroll
    for (int j = 0; j < 8; ++j) {
        float f = w[(size_t)(k0 + j) * 64 + c];
        short h = bfs(f);
        hi[j] = h;
        lo[j] = bfs(f - bff(h));
    }
}

// ---------------------------------------------------------------------------
// Fast zero of the pooled accumulator (in-graph; ~5 us at HBM write BW).
// ---------------------------------------------------------------------------
__global__ __launch_bounds__(256) void zero_kernel(f32x4* __restrict__ p, int n4)
{
    int i = blockIdx.x * blockDim.x + threadIdx.x;
    int stride = gridDim.x * blockDim.x;
    f32x4 z = {0.f, 0.f, 0.f, 0.f};
    for (; i < n4; i += stride) p[i] = z;
}

// ---------------------------------------------------------------------------
// phi via bf16 MFMA (unchanged from round 11; ~85 us).
// L1: x-hi/lo x W1-hi/lo = 12 MFMA; h1 staged bf16; L2: 16 MFMA.
// Contiguous-stream pooling: flushes only at true event boundaries.
// MFMA layouts (m89/m91-verified): A: row=l&15, k=8*(l>>4)+j; B: col=l&15,
// k=8*(l>>4)+j; C/D: col=l&15, row=4*(l>>4)+reg.
// ---------------------------------------------------------------------------
__global__ __launch_bounds__(256, 4) void phi_mfma_kernel(
    const float* __restrict__ x,
    const int*   __restrict__ eids,
    const float* __restrict__ w1, const float* __restrict__ b1,
    const float* __restrict__ w2, const float* __restrict__ b2,
    float* __restrict__ pooled, int n_tracks)
{
    __shared__ s16x8 wfrag[16][64];          // W2 frags: [4s+n]=hi, [8+4s+n]=lo
    __shared__ short h1s[4][16 * H1W];       // bf16 h1, per-wave slice

    const int lane = threadIdx.x & 63;
    const int wv   = threadIdx.x >> 6;
    const int g    = lane >> 4;
    const int r    = lane & 15;
    const int sg   = r >> 2;
    const int so   = r & 3;

    #pragma unroll
    for (int ff = 0; ff < 4; ++ff) {
        int f   = wv + 4 * ff;
        int idx = f & 7;
        int s   = idx >> 2;
        int n   = idx & 3;
        bool lo = (f >= 8);
        s16x8 v;
        #pragma unroll
        for (int j = 0; j < 8; ++j) {
            float fv = w2[(size_t)(32 * s + 8 * g + j) * 64 + (r + 16 * n)];
            short h  = bfs(fv);
            v[j] = lo ? bfs(fv - bff(h)) : h;
        }
        wfrag[f][lane] = v;
    }
    __syncthreads();

    short* h1w = h1s[wv];
    const long long wbase = ((long long)blockIdx.x * 4 + wv) * (4LL * STREAM);
    if (wbase >= n_tracks) return;

    s16x8 w1h[4], w1l[4];
    #pragma unroll
    for (int n = 0; n < 4; ++n) load_bfrag(w1, 8 * g, r + 16 * n, w1h[n], w1l[n]);

    float b1v[4], b2v[4];
    #pragma unroll
    for (int n = 0; n < 4; ++n) { b1v[n] = b1[r + 16 * n]; b2v[n] = b2[r + 16 * n]; }

    #define LOADX(T, XA, XB) {                                                    \
        long long row_ = wbase + (long long)sg * STREAM + 4 * (T) + so;           \
        if (row_ > n_tracks - 1) row_ = n_tracks - 1;                             \
        XA = *(const f32x4*)(x + row_ * N_FEAT + 8 * g);                          \
        XB = *(const f32x4*)(x + row_ * N_FEAT + 8 * g + 4);                      \
    }

    f32x4 xa, xb;
    LOADX(0, xa, xb)

    float carry[4] = {0.f, 0.f, 0.f, 0.f};
    int carry_id = -1;
    int dyn = 0;

    #pragma unroll 1
    for (int t = 0; t < TILES_PER_WAVE; ++t) {
        asm volatile("" : "+v"(dyn));
        const s16x8* wfl = (const s16x8*)&wfrag[0][lane] + dyn;

        long long tbg = wbase + (long long)g * STREAM + 4 * t;
        long long ib = tbg;
        if (ib > n_tracks - 4) ib = (n_tracks - 4) & ~3LL;
        i32x4 e4 = *(const i32x4*)(eids + ib);

        s16x8 xh, xl;
        split8(xa, xb, xh, xl);
        if (t + 1 < TILES_PER_WAVE) LOADX(t + 1, xa, xb)

        f32x4 h1C[4];
        #pragma unroll
        for (int n = 0; n < 4; ++n) {
            f32x4 c = {0.f, 0.f, 0.f, 0.f};
            c = mfma16(xl, w1h[n], c);
            c = mfma16(xh, w1l[n], c);
            c = mfma16(xh, w1h[n], c);
            h1C[n] = c;
        }

        #pragma unroll
        for (int n = 0; n < 4; ++n)
            #pragma unroll
            for (int q = 0; q < 4; ++q)
                h1w[(4 * g + q) * H1W + r + 16 * n] =
                    bfs(fmaxf(h1C[n][q] + b1v[n], 0.f));

        s16x8 ah0 = *(const s16x8*)&h1w[r * H1W + 8 * g];
        s16x8 ah1 = *(const s16x8*)&h1w[r * H1W + 32 + 8 * g];

        f32x4 h2C[4] = {{0.f,0.f,0.f,0.f},{0.f,0.f,0.f,0.f},{0.f,0.f,0.f,0.f},{0.f,0.f,0.f,0.f}};
        #pragma unroll
        for (int n = 0; n < 4; ++n) {
            h2C[n] = mfma16(ah0, wfl[64 * (8 + n)], h2C[n]);
            h2C[n] = mfma16(ah0, wfl[64 * n],       h2C[n]);
            h2C[n] = mfma16(ah1, wfl[64 * (12 + n)], h2C[n]);
            h2C[n] = mfma16(ah1, wfl[64 * (4 + n)],  h2C[n]);
        }

        int remg = (int)(n_tracks - tbg);
        remg = remg < 0 ? 0 : (remg > 4 ? 4 : remg);
        const bool newrun   = (e4[0] != carry_id);
        const bool doflush0 = newrun && (carry_id >= 0);
        const bool q01 = (e4[1] != e4[0]);
        const bool q12 = (e4[2] != e4[1]);
        const bool q23 = (e4[3] != e4[2]);
        #pragma unroll
        for (int n = 0; n < 4; ++n) {
            f32x4 hv;
            #pragma unroll
            for (int q = 0; q < 4; ++q) {
                float fq = fmaxf(h2C[n][q] + b2v[n], 0.f);
                hv[q] = (q < remg) ? fq : 0.f;
            }
            float* pp = pooled + (size_t)(r + 16 * n);
            float c = carry[n];
            if (doflush0) atomicAdd(pp + (size_t)carry_id * N_LAT, c);
            if (newrun)   c = 0.f;
            c += hv[0];
            if (q01) { atomicAdd(pp + (size_t)e4[0] * N_LAT, c); c = 0.f; }
            c += hv[1];
            if (q12) { atomicAdd(pp + (size_t)e4[1] * N_LAT, c); c = 0.f; }
            c += hv[2];
            if (q23) { atomicAdd(pp + (size_t)e4[2] * N_LAT, c); c = 0.f; }
            c += hv[3];
            carry[n] = c;
        }
        carry_id = e4[3];
    }

    if (carry_id >= 0) {
        #pragma unroll
        for (int n = 0; n < 4; ++n)
            atomicAdd(pooled + (size_t)carry_id * N_LAT + r + 16 * n, carry[n]);
    }
    #undef LOADX
}

// ---------------------------------------------------------------------------
// rho stage 1 via MFMA: r1 = relu(pooled @ W1 + b1)   [16-event tile/wave]
// Round-13: old readlane rho was ~125 us (the real top consumer; the round-11
// "memset 148us" was a non-graph artifact). A: pooled hi/lo (4 f32x4 loads,
// split); B: W1 hi/lo frags in LDS (2 ks x 8 nt x 2 = 32 KB); 48 MFMA/tile.
// r1 staged to LDS bf16 row-major, written coalesced to global (bf16 rows
// are rho2's ready A-frags -- same trick as phi's h1).
// ---------------------------------------------------------------------------
__global__ __launch_bounds__(256, 3) void rho1_kernel(
    const float* __restrict__ pooled,
    const float* __restrict__ w1, const float* __restrict__ b1,
    short* __restrict__ r1g, int n_events)
{
    __shared__ s16x8 wf[32][64];            // [plane*16 + ks*8 + nt], 32 KB
    __shared__ short st[4][16 * R1W];       // per-wave r1 staging (4.35 KB each)

    const int lane = threadIdx.x & 63;
    const int wv   = threadIdx.x >> 6;
    const int g    = lane >> 4;
    const int r    = lane & 15;

    // cooperative pack: W1 [64][128] row-major; col c = r+16nt, k0 = 32ks+8g
    #pragma unroll
    for (int ff = 0; ff < 8; ++ff) {
        int f = wv + 4 * ff;
        int plane = f >> 4;                 // 0 hi, 1 lo
        int idx = f & 15;
        int ks = idx >> 3, nt = idx & 7;
        s16x8 v;
        #pragma unroll
        for (int j = 0; j < 8; ++j) {
            float fv = w1[(size_t)(32 * ks + 8 * g + j) * R_HID + (r + 16 * nt)];
            short h  = bfs(fv);
            v[j] = plane ? bfs(fv - bff(h)) : h;
        }
        wf[f][lane] = v;
    }
    __syncthreads();

    const long long ebase = ((long long)blockIdx.x * 4 + wv) * 16;
    if (ebase >= n_events) return;          // after barrier -> safe

    // A-frags: pooled row ebase+r, k-halves 8g.. and 32+8g..
    long long prow = ebase + r; if (prow > n_events - 1) prow = n_events - 1;
    const f32x4* pr = (const f32x4*)(pooled + prow * N_LAT);
    s16x8 xh0, xl0, xh1, xl1;
    split8(pr[2 * g],     pr[2 * g + 1], xh0, xl0);
    split8(pr[8 + 2 * g], pr[9 + 2 * g], xh1, xl1);

    short* stw = st[wv];
    #pragma unroll
    for (int nt = 0; nt < 8; ++nt) {
        s16x8 wh0 = wf[nt][lane],      wl0 = wf[16 + nt][lane];
        s16x8 wh1 = wf[8 + nt][lane],  wl1 = wf[24 + nt][lane];
        f32x4 c = {0.f, 0.f, 0.f, 0.f};
        c = mfma16(xl0, wh0, c);
        c = mfma16(xh0, wl0, c);
        c = mfma16(xh0, wh0, c);
        c = mfma16(xl1, wh1, c);
        c = mfma16(xh1, wl1, c);
        c = mfma16(xh1, wh1, c);
        float bv = b1[r + 16 * nt];
        #pragma unroll
        for (int q = 0; q < 4; ++q)
            stw[(4 * g + q) * R1W + r + 16 * nt] = bfs(fmaxf(c[q] + bv, 0.f));
    }

    // coalesced write-out: 256 b128 chunks (16 rows x 16 chunks), 4 per lane
    #pragma unroll
    for (int i = 0; i < 4; ++i) {
        int chunk = 64 * i + lane;
        int row = chunk >> 4;
        int off = (chunk & 15) * 8;
        s16x8 v = *(const s16x8*)&stw[row * R1W + off];
        long long er = ebase + row;
        if (er < n_events) *(s16x8*)(r1g + er * R_HID + off) = v;
    }
}

// ---------------------------------------------------------------------------
// rho stage 2 via MFMA: out = sigmoid(relu(r1 @ W2 + b2) . w3 + b3).
// A-frags read directly from r1g bf16 rows (4 b128/lane); W2 hi/lo frags in
// LDS (4 ks x 4 nt x 2 = 32 KB); 32 MFMA/tile. L3 = per-lane partial over nt
// + 4-step shfl_xor row-reduce + sigmoid.
// ---------------------------------------------------------------------------
__global__ __launch_bounds__(256, 4) void rho2_kernel(
    const short* __restrict__ r1g,
    const float* __restrict__ w2, const float* __restrict__ b2,
    const float* __restrict__ w3, const float* __restrict__ b3,
    float* __restrict__ out, int n_events)
{
    __shared__ s16x8 wf[32][64];            // [plane*16 + ks*4 + nt], 32 KB

    const int lane = threadIdx.x & 63;
    const int wv   = threadIdx.x >> 6;
    const int g    = lane >> 4;
    const int r    = lane & 15;

    // cooperative pack: W2 [128][64] row-major; col c = r+16nt, k0 = 32ks+8g
    #pragma unroll
    for (int ff = 0; ff < 8; ++ff) {
        int f = wv + 4 * ff;
        int plane = f >> 4;
        int idx = f & 15;
        int ks = idx >> 2, nt = idx & 3;
        s16x8 v;
        #pragma unroll
        for (int j = 0; j < 8; ++j) {
            float fv = w2[(size_t)(32 * ks + 8 * g + j) * N_LAT + (r + 16 * nt)];
            short h  = bfs(fv);
            v[j] = plane ? bfs(fv - bff(h)) : h;
        }
        wf[f][lane] = v;
    }
    __syncthreads();

    const long long ebase = ((long long)blockIdx.x * 4 + wv) * 16;
    if (ebase >= n_events) return;          // after barrier -> safe

    long long arow = ebase + r; if (arow > n_events - 1) arow = n_events - 1;
    s16x8 ah[4];
    #pragma unroll
    for (int ks = 0; ks < 4; ++ks)
        ah[ks] = *(const s16x8*)(r1g + arow * R_HID + 32 * ks + 8 * g);

    float s0 = 0.f, s1 = 0.f, s2 = 0.f, s3 = 0.f;
    #pragma unroll
    for (int nt = 0; nt < 4; ++nt) {
        f32x4 c = {0.f, 0.f, 0.f, 0.f};
        #pragma unroll
        for (int ks = 0; ks < 4; ++ks) {
            c = mfma16(ah[ks], wf[16 + ks * 4 + nt][lane], c);   // lo
            c = mfma16(ah[ks], wf[ks * 4 + nt][lane],      c);   // hi
        }
        float bv = b2[r + 16 * nt];
        float wv3 = w3[r + 16 * nt];
        s0 = fmaf(fmaxf(c[0] + bv, 0.f), wv3, s0);
        s1 = fmaf(fmaxf(c[1] + bv, 0.f), wv3, s1);
        s2 = fmaf(fmaxf(c[2] + bv, 0.f), wv3, s2);
        s3 = fmaf(fmaxf(c[3] + bv, 0.f), wv3, s3);
    }
    // reduce over the 16 lanes of group g (r dimension = columns)
    #pragma unroll
    for (int off = 1; off < 16; off <<= 1) {
        s0 += __shfl_xor(s0, off, 64);
        s1 += __shfl_xor(s1, off, 64);
        s2 += __shfl_xor(s2, off, 64);
        s3 += __shfl_xor(s3, off, 64);
    }
    if (r == 0) {
        float b3v = b3[0];
        float zs[4] = {s0, s1, s2, s3};
        #pragma unroll
        for (int q = 0; q < 4; ++q) {
            long long e = ebase + 4 * g + q;
            if (e < n_events) out[e] = 1.f / (1.f + expf(-(zs[q] + b3v)));
        }
    }
}

extern "C" void kernel_launch(void* const* d_in, const int* in_sizes, int n_in,
                              void* d_out, int out_size, void* d_ws, size_t ws_size,
                              hipStream_t stream) {
    const float* x      = (const float*)d_in[0];
    const int*   eids   = (const int*)  d_in[1];
    const float* phi_w1 = (const float*)d_in[2];
    const float* phi_b1 = (const float*)d_in[3];
    const float* phi_w2 = (const float*)d_in[4];
    const float* phi_b2 = (const float*)d_in[5];
    const float* rho_w1 = (const float*)d_in[6];
    const float* rho_b1 = (const float*)d_in[7];
    const float* rho_w2 = (const float*)d_in[8];
    const float* rho_b2 = (const float*)d_in[9];
    const float* rho_w3 = (const float*)d_in[10];
    const float* rho_b3 = (const float*)d_in[11];
    float* out = (float*)d_out;

    int n_tracks = in_sizes[1];
    int n_events = out_size;

    float* pooled = (float*)d_ws;                                  // 25.6 MB f32
    short* r1g    = (short*)((char*)d_ws +
                    (size_t)n_events * N_LAT * sizeof(float));     // 25.6 MB bf16

    int n4 = n_events * N_LAT / 4;
    zero_kernel<<<2048, 256, 0, stream>>>((f32x4*)pooled, n4);

    long long tracks_per_wave = 4LL * STREAM;   // 128
    long long waves  = ((long long)n_tracks + tracks_per_wave - 1) / tracks_per_wave;
    int phi_blocks   = (int)((waves + 3) / 4);
    phi_mfma_kernel<<<phi_blocks, 256, 0, stream>>>(
        x, eids, phi_w1, phi_b1, phi_w2, phi_b2, pooled, n_tracks);

    long long tiles = ((long long)n_events + 15) / 16;
    int rho_blocks = (int)((tiles + 3) / 4);
    rho1_kernel<<<rho_blocks, 256, 0, stream>>>(
        pooled, rho_w1, rho_b1, r1g, n_events);
    rho2_kernel<<<rho_blocks, 256, 0, stream>>>(
        r1g, rho_w2, rho_b2, rho_w3, rho_b3, out, n_events);
}

// Round 14
// 115.061 us; speedup vs baseline: 1.9060x; 1.0868x over previous
//
#include <hip/hip_runtime.h>
#include <hip/hip_bf16.h>
#include <math.h>

#define N_FEAT 32
#define N_HID  64   // 2*N_FEAT
#define N_LAT  64
#define R_HID  128  // 2*N_LAT
#define TILES_PER_WAVE 16   // 256 tracks/wave -> 7813 waves (~7.6/SIMD queued;
                            // halves end-of-stream flushes + prologue overhead
                            // vs 8; round-6 starvation was at 3.8/SIMD)
#define STREAM (4 * TILES_PER_WAVE)   // 64 contiguous tracks per lane-group
#define H1W 88              // h1 bf16 row stride in shorts (176B, aligned b128 rows)
#define R1W 136             // r1 bf16 row stride in shorts (272B, b128-aligned rows)

typedef short s16x8 __attribute__((ext_vector_type(8)));
typedef float f32x4 __attribute__((ext_vector_type(4)));
typedef int   i32x4 __attribute__((ext_vector_type(4)));

__device__ __forceinline__ short bfs(float f) {          // f32 -> bf16 bits (RNE)
    __bf16 b = (__bf16)f;
    return __builtin_bit_cast(short, b);
}
__device__ __forceinline__ float bff(short s) {          // bf16 bits -> f32 (exact)
    return (float)__builtin_bit_cast(__bf16, s);
}
__device__ __forceinline__ f32x4 mfma16(s16x8 a, s16x8 b, f32x4 c) {
    return __builtin_amdgcn_mfma_f32_16x16x32_bf16(a, b, c, 0, 0, 0);
}
__device__ __forceinline__ void split8(f32x4 a, f32x4 b, s16x8& h, s16x8& l) {
    #pragma unroll
    for (int j = 0; j < 4; ++j) {
        short h0 = bfs(a[j]); h[j] = h0;     l[j] = bfs(a[j] - bff(h0));
        short h1 = bfs(b[j]); h[4 + j] = h1; l[4 + j] = bfs(b[j] - bff(h1));
    }
}
__device__ __forceinline__ s16x8 pack8(f32x4 a, f32x4 b) {   // hi-only (round-14)
    s16x8 h;
    #pragma unroll
    for (int j = 0; j < 4; ++j) { h[j] = bfs(a[j]); h[4 + j] = bfs(b[j]); }
    return h;
}

// B-frag loader: lane (g,r), tile col c: b[j] = w[(k0+j)*64 + c], split hi/lo.
__device__ __forceinline__ void load_bfrag(const float* __restrict__ w, int k0, int c,
                                           s16x8& hi, s16x8& lo) {
    #pragma unroll
    for (int j = 0; j < 8; ++j) {
        float f = w[(size_t)(k0 + j) * 64 + c];
        short h = bfs(f);
        hi[j] = h;
        lo[j] = bfs(f - bff(h));
    }
}

// ---------------------------------------------------------------------------
// Fast zero of the pooled accumulator (in-graph; ~5 us at HBM write BW).
// ---------------------------------------------------------------------------
__global__ __launch_bounds__(256) void zero_kernel(f32x4* __restrict__ p, int n4)
{
    int i = blockIdx.x * blockDim.x + threadIdx.x;
    int stride = gridDim.x * blockDim.x;
    f32x4 z = {0.f, 0.f, 0.f, 0.f};
    for (; i < n4; i += stride) p[i] = z;
}

// ---------------------------------------------------------------------------
// phi via bf16 MFMA. Round-14 precision: x plain bf16 (dropped x_lo; adds
// ~2^-9-relative on h1, same order as the existing bf16-h1 staging; absmax
// margin was 5x). L1: xh x W1-hi/lo = 8 MFMA; h1 staged bf16; L2: 16 MFMA.
// Contiguous-stream pooling (round-11-validated: dur tracks flush traffic).
// MFMA layouts (m89/m91-verified): A: row=l&15, k=8*(l>>4)+j; B: col=l&15,
// k=8*(l>>4)+j; C/D: col=l&15, row=4*(l>>4)+reg.
// ---------------------------------------------------------------------------
__global__ __launch_bounds__(256, 4) void phi_mfma_kernel(
    const float* __restrict__ x,
    const int*   __restrict__ eids,
    const float* __restrict__ w1, const float* __restrict__ b1,
    const float* __restrict__ w2, const float* __restrict__ b2,
    float* __restrict__ pooled, int n_tracks)
{
    __shared__ s16x8 wfrag[16][64];          // W2 frags: [4s+n]=hi, [8+4s+n]=lo
    __shared__ short h1s[4][16 * H1W];       // bf16 h1, per-wave slice

    const int lane = threadIdx.x & 63;
    const int wv   = threadIdx.x >> 6;
    const int g    = lane >> 4;
    const int r    = lane & 15;
    const int sg   = r >> 2;      // stream of A-row r
    const int so   = r & 3;       // offset within the stream's 4-track window

    #pragma unroll
    for (int ff = 0; ff < 4; ++ff) {
        int f   = wv + 4 * ff;
        int idx = f & 7;
        int s   = idx >> 2;
        int n   = idx & 3;
        bool lo = (f >= 8);
        s16x8 v;
        #pragma unroll
        for (int j = 0; j < 8; ++j) {
            float fv = w2[(size_t)(32 * s + 8 * g + j) * 64 + (r + 16 * n)];
            short h  = bfs(fv);
            v[j] = lo ? bfs(fv - bff(h)) : h;
        }
        wfrag[f][lane] = v;
    }
    __syncthreads();

    short* h1w = h1s[wv];
    const long long wbase = ((long long)blockIdx.x * 4 + wv) * (4LL * STREAM);
    if (wbase >= n_tracks) return;   // after the only barrier -> safe

    // W1 hi/lo frags in VGPRs (32 regs)
    s16x8 w1h[4], w1l[4];
    #pragma unroll
    for (int n = 0; n < 4; ++n) load_bfrag(w1, 8 * g, r + 16 * n, w1h[n], w1l[n]);

    float b1v[4], b2v[4];
    #pragma unroll
    for (int n = 0; n < 4; ++n) { b1v[n] = b1[r + 16 * n]; b2v[n] = b2[r + 16 * n]; }

    // x loader: A-row r of tile T <- track wbase + sg*STREAM + 4T + so
    #define LOADX(T, XA, XB) {                                                    \
        long long row_ = wbase + (long long)sg * STREAM + 4 * (T) + so;           \
        if (row_ > n_tracks - 1) row_ = n_tracks - 1;                             \
        XA = *(const f32x4*)(x + row_ * N_FEAT + 8 * g);                          \
        XB = *(const f32x4*)(x + row_ * N_FEAT + 8 * g + 4);                      \
    }

    f32x4 xa, xb;
    LOADX(0, xa, xb)

    float carry[4] = {0.f, 0.f, 0.f, 0.f};
    int carry_id = -1;
    int dyn = 0;   // opaque 0: keeps wfrag reads per-tile (defeats LICM reg-hoist)

    #pragma unroll 1
    for (int t = 0; t < TILES_PER_WAVE; ++t) {
        asm volatile("" : "+v"(dyn));
        const s16x8* wfl = (const s16x8*)&wfrag[0][lane] + dyn;

        long long tbg = wbase + (long long)g * STREAM + 4 * t;   // group window
        long long ib = tbg;
        if (ib > n_tracks - 4) ib = (n_tracks - 4) & ~3LL;
        i32x4 e4 = *(const i32x4*)(eids + ib);

        // pack current x to bf16 A-frag; prefetch next tile
        s16x8 xh = pack8(xa, xb);
        if (t + 1 < TILES_PER_WAVE) LOADX(t + 1, xa, xb)

        // layer 1: 8 MFMA (W1 hi/lo from regs)
        f32x4 h1C[4];
        #pragma unroll
        for (int n = 0; n < 4; ++n) {
            f32x4 c = {0.f, 0.f, 0.f, 0.f};
            c = mfma16(xh, w1l[n], c);
            c = mfma16(xh, w1h[n], c);
            h1C[n] = c;
        }

        // bias+relu, stage h1 as bf16
        #pragma unroll
        for (int n = 0; n < 4; ++n)
            #pragma unroll
            for (int q = 0; q < 4; ++q)
                h1w[(4 * g + q) * H1W + r + 16 * n] =
                    bfs(fmaxf(h1C[n][q] + b1v[n], 0.f));

        // read back h1 rows: 2 b128 = ready A-frags
        s16x8 ah0 = *(const s16x8*)&h1w[r * H1W + 8 * g];        // k = 0..31
        s16x8 ah1 = *(const s16x8*)&h1w[r * H1W + 32 + 8 * g];   // k = 32..63

        // layer 2: 16 MFMA (W2 hi/lo frags from LDS)
        f32x4 h2C[4] = {{0.f,0.f,0.f,0.f},{0.f,0.f,0.f,0.f},{0.f,0.f,0.f,0.f},{0.f,0.f,0.f,0.f}};
        #pragma unroll
        for (int n = 0; n < 4; ++n) {
            h2C[n] = mfma16(ah0, wfl[64 * (8 + n)], h2C[n]);       // lo s0
            h2C[n] = mfma16(ah0, wfl[64 * n],       h2C[n]);       // hi s0
            h2C[n] = mfma16(ah1, wfl[64 * (12 + n)], h2C[n]);      // lo s1
            h2C[n] = mfma16(ah1, wfl[64 * (4 + n)],  h2C[n]);      // hi s1
        }

        // bias+relu+pool: contiguous-stream run carry
        int remg = (int)(n_tracks - tbg);
        remg = remg < 0 ? 0 : (remg > 4 ? 4 : remg);
        const bool newrun   = (e4[0] != carry_id);
        const bool doflush0 = newrun && (carry_id >= 0);
        const bool q01 = (e4[1] != e4[0]);
        const bool q12 = (e4[2] != e4[1]);
        const bool q23 = (e4[3] != e4[2]);
        #pragma unroll
        for (int n = 0; n < 4; ++n) {
            f32x4 hv;
            #pragma unroll
            for (int q = 0; q < 4; ++q) {
                float fq = fmaxf(h2C[n][q] + b2v[n], 0.f);
                hv[q] = (q < remg) ? fq : 0.f;
            }
            float* pp = pooled + (size_t)(r + 16 * n);
            float c = carry[n];
            if (doflush0) atomicAdd(pp + (size_t)carry_id * N_LAT, c);
            if (newrun)   c = 0.f;
            c += hv[0];
            if (q01) { atomicAdd(pp + (size_t)e4[0] * N_LAT, c); c = 0.f; }
            c += hv[1];
            if (q12) { atomicAdd(pp + (size_t)e4[1] * N_LAT, c); c = 0.f; }
            c += hv[2];
            if (q23) { atomicAdd(pp + (size_t)e4[2] * N_LAT, c); c = 0.f; }
            c += hv[3];
            carry[n] = c;
        }
        carry_id = e4[3];
    }

    if (carry_id >= 0) {
        #pragma unroll
        for (int n = 0; n < 4; ++n)
            atomicAdd(pooled + (size_t)carry_id * N_LAT + r + 16 * n, carry[n]);
    }
    #undef LOADX
}

// ---------------------------------------------------------------------------
// rho stage 1 via MFMA (round-13-validated): r1 = relu(pooled @ W1 + b1).
// A: pooled hi/lo; B: W1 hi/lo frags in LDS (32 KB); 48 MFMA/tile; r1 staged
// to LDS bf16 row-major, coalesced to global (rows = rho2's ready A-frags).
// ---------------------------------------------------------------------------
__global__ __launch_bounds__(256, 3) void rho1_kernel(
    const float* __restrict__ pooled,
    const float* __restrict__ w1, const float* __restrict__ b1,
    short* __restrict__ r1g, int n_events)
{
    __shared__ s16x8 wf[32][64];            // [plane*16 + ks*8 + nt], 32 KB
    __shared__ short st[4][16 * R1W];       // per-wave r1 staging

    const int lane = threadIdx.x & 63;
    const int wv   = threadIdx.x >> 6;
    const int g    = lane >> 4;
    const int r    = lane & 15;

    #pragma unroll
    for (int ff = 0; ff < 8; ++ff) {
        int f = wv + 4 * ff;
        int plane = f >> 4;                 // 0 hi, 1 lo
        int idx = f & 15;
        int ks = idx >> 3, nt = idx & 7;
        s16x8 v;
        #pragma unroll
        for (int j = 0; j < 8; ++j) {
            float fv = w1[(size_t)(32 * ks + 8 * g + j) * R_HID + (r + 16 * nt)];
            short h  = bfs(fv);
            v[j] = plane ? bfs(fv - bff(h)) : h;
        }
        wf[f][lane] = v;
    }
    __syncthreads();

    const long long ebase = ((long long)blockIdx.x * 4 + wv) * 16;
    if (ebase >= n_events) return;

    long long prow = ebase + r; if (prow > n_events - 1) prow = n_events - 1;
    const f32x4* pr = (const f32x4*)(pooled + prow * N_LAT);
    s16x8 xh0, xl0, xh1, xl1;
    split8(pr[2 * g],     pr[2 * g + 1], xh0, xl0);
    split8(pr[8 + 2 * g], pr[9 + 2 * g], xh1, xl1);

    short* stw = st[wv];
    #pragma unroll
    for (int nt = 0; nt < 8; ++nt) {
        s16x8 wh0 = wf[nt][lane],      wl0 = wf[16 + nt][lane];
        s16x8 wh1 = wf[8 + nt][lane],  wl1 = wf[24 + nt][lane];
        f32x4 c = {0.f, 0.f, 0.f, 0.f};
        c = mfma16(xl0, wh0, c);
        c = mfma16(xh0, wl0, c);
        c = mfma16(xh0, wh0, c);
        c = mfma16(xl1, wh1, c);
        c = mfma16(xh1, wl1, c);
        c = mfma16(xh1, wh1, c);
        float bv = b1[r + 16 * nt];
        #pragma unroll
        for (int q = 0; q < 4; ++q)
            stw[(4 * g + q) * R1W + r + 16 * nt] = bfs(fmaxf(c[q] + bv, 0.f));
    }

    #pragma unroll
    for (int i = 0; i < 4; ++i) {
        int chunk = 64 * i + lane;
        int row = chunk >> 4;
        int off = (chunk & 15) * 8;
        s16x8 v = *(const s16x8*)&stw[row * R1W + off];
        long long er = ebase + row;
        if (er < n_events) *(s16x8*)(r1g + er * R_HID + off) = v;
    }
}

// ---------------------------------------------------------------------------
// rho stage 2 via MFMA (round-13-validated): out = sigmoid(relu(r1@W2+b2).w3+b3).
// ---------------------------------------------------------------------------
__global__ __launch_bounds__(256, 4) void rho2_kernel(
    const short* __restrict__ r1g,
    const float* __restrict__ w2, const float* __restrict__ b2,
    const float* __restrict__ w3, const float* __restrict__ b3,
    float* __restrict__ out, int n_events)
{
    __shared__ s16x8 wf[32][64];            // [plane*16 + ks*4 + nt], 32 KB

    const int lane = threadIdx.x & 63;
    const int wv   = threadIdx.x >> 6;
    const int g    = lane >> 4;
    const int r    = lane & 15;

    #pragma unroll
    for (int ff = 0; ff < 8; ++ff) {
        int f = wv + 4 * ff;
        int plane = f >> 4;
        int idx = f & 15;
        int ks = idx >> 2, nt = idx & 3;
        s16x8 v;
        #pragma unroll
        for (int j = 0; j < 8; ++j) {
            float fv = w2[(size_t)(32 * ks + 8 * g + j) * N_LAT + (r + 16 * nt)];
            short h  = bfs(fv);
            v[j] = plane ? bfs(fv - bff(h)) : h;
        }
        wf[f][lane] = v;
    }
    __syncthreads();

    const long long ebase = ((long long)blockIdx.x * 4 + wv) * 16;
    if (ebase >= n_events) return;

    long long arow = ebase + r; if (arow > n_events - 1) arow = n_events - 1;
    s16x8 ah[4];
    #pragma unroll
    for (int ks = 0; ks < 4; ++ks)
        ah[ks] = *(const s16x8*)(r1g + arow * R_HID + 32 * ks + 8 * g);

    float s0 = 0.f, s1 = 0.f, s2 = 0.f, s3 = 0.f;
    #pragma unroll
    for (int nt = 0; nt < 4; ++nt) {
        f32x4 c = {0.f, 0.f, 0.f, 0.f};
        #pragma unroll
        for (int ks = 0; ks < 4; ++ks) {
            c = mfma16(ah[ks], wf[16 + ks * 4 + nt][lane], c);   // lo
            c = mfma16(ah[ks], wf[ks * 4 + nt][lane],      c);   // hi
        }
        float bv = b2[r + 16 * nt];
        float wv3 = w3[r + 16 * nt];
        s0 = fmaf(fmaxf(c[0] + bv, 0.f), wv3, s0);
        s1 = fmaf(fmaxf(c[1] + bv, 0.f), wv3, s1);
        s2 = fmaf(fmaxf(c[2] + bv, 0.f), wv3, s2);
        s3 = fmaf(fmaxf(c[3] + bv, 0.f), wv3, s3);
    }
    #pragma unroll
    for (int off = 1; off < 16; off <<= 1) {
        s0 += __shfl_xor(s0, off, 64);
        s1 += __shfl_xor(s1, off, 64);
        s2 += __shfl_xor(s2, off, 64);
        s3 += __shfl_xor(s3, off, 64);
    }
    if (r == 0) {
        float b3v = b3[0];
        float zs[4] = {s0, s1, s2, s3};
        #pragma unroll
        for (int q = 0; q < 4; ++q) {
            long long e = ebase + 4 * g + q;
            if (e < n_events) out[e] = 1.f / (1.f + expf(-(zs[q] + b3v)));
        }
    }
}

extern "C" void kernel_launch(void* const* d_in, const int* in_sizes, int n_in,
                              void* d_out, int out_size, void* d_ws, size_t ws_size,
                              hipStream_t stream) {
    const float* x      = (const float*)d_in[0];
    const int*   eids   = (const int*)  d_in[1];
    const float* phi_w1 = (const float*)d_in[2];
    const float* phi_b1 = (const float*)d_in[3];
    const float* phi_w2 = (const float*)d_in[4];
    const float* phi_b2 = (const float*)d_in[5];
    const float* rho_w1 = (const float*)d_in[6];
    const float* rho_b1 = (const float*)d_in[7];
    const float* rho_w2 = (const float*)d_in[8];
    const float* rho_b2 = (const float*)d_in[9];
    const float* rho_w3 = (const float*)d_in[10];
    const float* rho_b3 = (const float*)d_in[11];
    float* out = (float*)d_out;

    int n_tracks = in_sizes[1];
    int n_events = out_size;

    float* pooled = (float*)d_ws;                                  // 25.6 MB f32
    short* r1g    = (short*)((char*)d_ws +
                    (size_t)n_events * N_LAT * sizeof(float));     // 25.6 MB bf16

    int n4 = n_events * N_LAT / 4;
    zero_kernel<<<2048, 256, 0, stream>>>((f32x4*)pooled, n4);

    long long tracks_per_wave = 4LL * STREAM;   // 256
    long long waves  = ((long long)n_tracks + tracks_per_wave - 1) / tracks_per_wave;
    int phi_blocks   = (int)((waves + 3) / 4);
    phi_mfma_kernel<<<phi_blocks, 256, 0, stream>>>(
        x, eids, phi_w1, phi_b1, phi_w2, phi_b2, pooled, n_tracks);

    long long tiles = ((long long)n_events + 15) / 16;
    int rho_blocks = (int)((tiles + 3) / 4);
    rho1_kernel<<<rho_blocks, 256, 0, stream>>>(
        pooled, rho_w1, rho_b1, r1g, n_events);
    rho2_kernel<<<rho_blocks, 256, 0, stream>>>(
        r1g, rho_w2, rho_b2, rho_w3, rho_b3, out, n_events);
}